// Round 5
// baseline (381.290 us; speedup 1.0000x reference)
//
#include <hip/hip_runtime.h>
#include <hip/hip_bf16.h>

typedef short bf16x8 __attribute__((ext_vector_type(8)));
typedef float f32x4 __attribute__((ext_vector_type(4)));

#define BSH 7            // 128 targets per bucket
#define BK  (1 << BSH)

static inline int cdiv(int a, int b){ return (a + b - 1) / b; }

__device__ __forceinline__ unsigned pack_bf16_hi(float v){
    return ((unsigned)__bfloat16_as_ushort(__float2bfloat16(v))) << 16;
}
__device__ __forceinline__ float bf16hi_to_f32(unsigned bits_hi16){
    return __uint_as_float(bits_hi16);  // bf16 bits already in [31:16]
}

// ---------- pass 0: global bucket histogram (LDS-privatized) ----------
__global__ __launch_bounds__(256) void k_bcnt0(const int* __restrict__ tgt,
                                               int* __restrict__ gcnt, int E, int NB){
    __shared__ int lh[1024];
    int tid = threadIdx.x;
    for (int b = tid; b < 1024; b += 256) lh[b] = 0;
    __syncthreads();
    int c0 = blockIdx.x * 4096;
    #pragma unroll
    for (int u = 0; u < 16; ++u){
        int e = c0 + u * 256 + tid;
        if (e < E) atomicAdd(&lh[tgt[e] >> BSH], 1);
    }
    __syncthreads();
    for (int b = tid; b < NB; b += 256){
        int c = lh[b];
        if (c) atomicAdd(&gcnt[b], c);
    }
}

// ---------- pass 0.5: scan bucket counts -> bases (= CSR bucket bases) ----------
__global__ __launch_bounds__(256) void k_bscan(const int* __restrict__ gcnt,
                                               int* __restrict__ bbase,
                                               int* __restrict__ gcur,
                                               int* __restrict__ rs,
                                               int N, int E){
    __shared__ int sc[256];
    int tid = threadIdx.x;
    int b0 = tid * 4;
    int v0 = gcnt[b0], v1 = gcnt[b0 + 1], v2 = gcnt[b0 + 2], v3 = gcnt[b0 + 3];
    int t3 = v0 + v1 + v2 + v3;
    sc[tid] = t3;
    __syncthreads();
    for (int off = 1; off < 256; off <<= 1){
        int x = (tid >= off) ? sc[tid - off] : 0;
        __syncthreads();
        sc[tid] += x;
        __syncthreads();
    }
    int ex = sc[tid] - t3;
    bbase[b0]     = ex;
    bbase[b0 + 1] = ex + v0;
    bbase[b0 + 2] = ex + v0 + v1;
    bbase[b0 + 3] = ex + v0 + v1 + v2;
    gcur[b0] = bbase[b0]; gcur[b0 + 1] = bbase[b0 + 1];
    gcur[b0 + 2] = bbase[b0 + 2]; gcur[b0 + 3] = bbase[b0 + 3];
    if (tid == 255) bbase[1024] = sc[255];   // == E
    if (tid == 0)   rs[N] = E;
}

// ---------- pass 1: bin edges into bucket-contiguous regions (direct write) ----------
__global__ __launch_bounds__(256) void k_bin(
        const int* __restrict__ src, const int* __restrict__ tgt,
        const float* __restrict__ asp, const float* __restrict__ actx,
        const float* __restrict__ alat, const float* __restrict__ wsp,
        const float* __restrict__ wctx, const float* __restrict__ wlat,
        int* __restrict__ gcur, uint4* __restrict__ binned, int E, int NB){
    __shared__ int lh[1024], lc[1024], gb[1024];
    int tid = threadIdx.x;
    int c0 = blockIdx.x * 4096;
    for (int b = tid; b < 1024; b += 256){ lh[b] = 0; lc[b] = 0; }
    __syncthreads();
    #pragma unroll
    for (int u = 0; u < 16; ++u){
        int e = c0 + u * 256 + tid;
        if (e < E) atomicAdd(&lh[tgt[e] >> BSH], 1);
    }
    __syncthreads();
    for (int b = tid; b < NB; b += 256){
        int c = lh[b];
        gb[b] = c ? atomicAdd(&gcur[b], c) : 0;
    }
    __syncthreads();
    #pragma unroll
    for (int u = 0; u < 16; ++u){
        int e = c0 + u * 256 + tid;
        if (e < E){
            int t = tgt[e];
            int b = t >> BSH;
            int p = gb[b] + atomicAdd(&lc[b], 1);
            uint4 o;
            o.x = (unsigned)src[e] | pack_bf16_hi(asp[e] * wsp[e]);
            o.y = (pack_bf16_hi(actx[e] * wctx[e]) >> 16) | pack_bf16_hi(alat[e] * wlat[e]);
            o.z = (unsigned)t;
            o.w = 0u;
            binned[p] = o;
        }
    }
}

// ---------- pass 2: per-bucket CSR finalize (writes rs + final effo)
//            + fused per-target deg sums -> dinv_all for ALL layers ----------
__global__ __launch_bounds__(256) void k_bucket(
        const uint4* __restrict__ binned, const int* __restrict__ bbase,
        const float* __restrict__ dp,        // [L*3]
        uint2* __restrict__ effo, int* __restrict__ rs,
        float* __restrict__ dinv_all,        // [L][N][4] (padded float4)
        int N, int L){
    __shared__ int th[128], sc2[128], cur[128];
    __shared__ float sm[384];
    int tid = threadIdx.x;
    int b = blockIdx.x;
    int t0 = b << BSH;
    int ebeg = bbase[b], eend = bbase[b + 1];
    if (tid < 128) th[tid] = 0;
    for (int j = tid; j < 384; j += 256) sm[j] = 0.f;
    __syncthreads();
    for (int i = ebeg + tid; i < eend; i += 256)
        atomicAdd(&th[(int)binned[i].z - t0], 1);
    __syncthreads();
    int v = (tid < 128) ? th[tid] : 0;
    if (tid < 128) sc2[tid] = v;
    __syncthreads();
    for (int off = 1; off < 128; off <<= 1){
        int x = (tid >= off && tid < 128) ? sc2[tid - off] : 0;
        __syncthreads();
        if (tid < 128) sc2[tid] += x;
        __syncthreads();
    }
    if (tid < 128){
        int exv = sc2[tid] - v;
        cur[tid] = exv;
        int t = t0 + tid;
        if (t < N) rs[t] = ebeg + exv;
    }
    __syncthreads();
    for (int i = ebeg + tid; i < eend; i += 256){
        uint4 r = binned[i];
        int loc = (int)r.z - t0;
        int p = atomicAdd(&cur[loc], 1);
        uint2 o = {r.x, r.y};
        effo[ebeg + p] = o;
        atomicAdd(&sm[loc * 3 + 0], bf16hi_to_f32(r.x & 0xFFFF0000u));
        atomicAdd(&sm[loc * 3 + 1], bf16hi_to_f32(r.y << 16));
        atomicAdd(&sm[loc * 3 + 2], bf16hi_to_f32(r.y & 0xFFFF0000u));
    }
    __syncthreads();
    if (tid < 128){
        int t = t0 + tid;
        if (t < N){
            float d0 = fmaxf(1.f + sm[tid * 3 + 0], 1e-6f);
            float d1 = fmaxf(1.f + sm[tid * 3 + 1], 1e-6f);
            float d2 = fmaxf(1.f + sm[tid * 3 + 2], 1e-6f);
            for (int l = 0; l < L; ++l){
                size_t base = ((size_t)l * N + t) * 4;
                dinv_all[base + 0] = powf(d0, dp[l * 3 + 0]);
                dinv_all[base + 1] = powf(d1, dp[l * 3 + 1]);
                dinv_all[base + 2] = powf(d2, dp[l * 3 + 2]);
                dinv_all[base + 3] = 0.f;
            }
        }
    }
}

// -------- merged prep: x (fp32) -> A'[:,0:128] bf16  AND  BT concat (one launch) ----
__global__ void k_prep(const float* __restrict__ x, __hip_bfloat16* __restrict__ Ap,
                       const float* __restrict__ Wself, const float* __restrict__ W3,
                       __hip_bfloat16* __restrict__ BT, int nx, int nw){
    int i = blockIdx.x * 256 + threadIdx.x;
    if (i < nx){
        Ap[(size_t)(i >> 7) * 512 + (i & 127)] = __float2bfloat16(x[i]);
    } else {
        int q = i - nx;
        if (q < nw){
            int l = q >> 16, r = q & 65535;
            int j = r >> 9, k = r & 511;
            float v;
            if (k < 128) v = Wself[l * 16384 + k * 128 + j];
            else {
                int c = (k >> 7) - 1, kk = k & 127;
                v = W3[l * 49152 + (c * 128 + kk) * 128 + j];
            }
            BT[q] = __float2bfloat16(v);
        }
    }
}

// ---------------- aggregate: Y_c[t] = dt_c * sum_e eff_c[e]*dinv_c[src]*x[src] ----
// v5 = round-0 structure (wave per target, 2 cols/lane, unroll-8: 28 VGPR, 62% occ,
// 48.6us measured) + dinv fold via plain loads at WAVE-UNIFORM addresses (all 64
// lanes read the same 16B dinv4[s] line -> one broadcast fill per edge, ~6MB total).
// No readfirstlane (removed as the only novel construct in the failed round-4 build).
__global__ __launch_bounds__(256) void k_msg(
        __hip_bfloat16* __restrict__ Ap,   // [N,512]: cols 0..127 = x (read), 128..511 = Y (write)
        const uint2* __restrict__ effo,    // [E] packed {src|e0, e1|e2}, CSR order
        const int* __restrict__ rs,        // [N+1]
        const float4* __restrict__ dinv4,  // [N] padded {d0,d1,d2,0} (this layer)
        int N){
    int w = threadIdx.x >> 6, lane = threadIdx.x & 63;
    int t = blockIdx.x * 4 + w;
    if (t >= N) return;
    float ax0 = 0.f, ay0 = 0.f, ax1 = 0.f, ay1 = 0.f, ax2 = 0.f, ay2 = 0.f;
    int beg = rs[t], end = rs[t + 1];
    int i = beg;
    for (; i + 8 <= end; i += 8){
        uint2 m[8];
        #pragma unroll
        for (int u = 0; u < 8; ++u) m[u] = effo[i + u];   // wave-uniform addr
        float2 f[8];
        #pragma unroll
        for (int u = 0; u < 8; ++u){
            const __hip_bfloat162* p =
                (const __hip_bfloat162*)(Ap + (size_t)(m[u].x & 0xFFFFu) * 512);
            f[u] = __bfloat1622float2(p[lane]);
        }
        #pragma unroll
        for (int u = 0; u < 8; ++u){
            float4 d = dinv4[m[u].x & 0xFFFFu];           // wave-uniform addr
            float n0 = bf16hi_to_f32(m[u].x & 0xFFFF0000u) * d.x;
            float n1 = bf16hi_to_f32(m[u].y << 16)         * d.y;
            float n2 = bf16hi_to_f32(m[u].y & 0xFFFF0000u) * d.z;
            ax0 += n0 * f[u].x; ay0 += n0 * f[u].y;
            ax1 += n1 * f[u].x; ay1 += n1 * f[u].y;
            ax2 += n2 * f[u].x; ay2 += n2 * f[u].y;
        }
    }
    for (; i < end; ++i){
        uint2 m = effo[i];
        const __hip_bfloat162* p =
            (const __hip_bfloat162*)(Ap + (size_t)(m.x & 0xFFFFu) * 512);
        float2 fv = __bfloat1622float2(p[lane]);
        float4 d = dinv4[m.x & 0xFFFFu];
        float n0 = bf16hi_to_f32(m.x & 0xFFFF0000u) * d.x;
        float n1 = bf16hi_to_f32(m.y << 16)         * d.y;
        float n2 = bf16hi_to_f32(m.y & 0xFFFF0000u) * d.z;
        ax0 += n0 * fv.x; ay0 += n0 * fv.y;
        ax1 += n1 * fv.x; ay1 += n1 * fv.y;
        ax2 += n2 * fv.x; ay2 += n2 * fv.y;
    }
    float4 dt = dinv4[t];
    __hip_bfloat162* yo = (__hip_bfloat162*)(Ap + (size_t)t * 512 + 128) + lane;
    float2 r0 = {dt.x * ax0, dt.x * ay0};
    float2 r1 = {dt.y * ax1, dt.y * ay1};
    float2 r2 = {dt.z * ax2, dt.z * ay2};
    yo[0]   = __float22bfloat162_rn(r0);
    yo[64]  = __float22bfloat162_rn(r1);
    yo[128] = __float22bfloat162_rn(r2);
}

// ---------------- GEMM: out = A'[M,512] @ B[512,128] + bias; optional fused LN+ReLU
// (round-2 int4-vector staging — the global_load_lds variant regressed ~5us)
__global__ __launch_bounds__(256) void k_gemm(
        const __hip_bfloat16* __restrict__ A,   // [M,512] bf16
        const __hip_bfloat16* __restrict__ BT,  // [128,512] bf16 ([j][k])
        const float* __restrict__ bias,         // [128] fp32
        float* __restrict__ outbuf,             // [M,128] (doLN==0)
        int M, int doLN,
        const float* __restrict__ g, const float* __restrict__ b,
        __hip_bfloat16* __restrict__ Ap){       // (doLN==1)
    __shared__ __hip_bfloat16 As[128 * 128];
    __shared__ __hip_bfloat16 Bs[128 * 128];
    const int tid = threadIdx.x;
    const int row0 = blockIdx.x * 128;
    const int w = tid >> 6, lane = tid & 63;
    const int wm = (w & 1) * 64, wn = (w >> 1) * 64;
    const int lm = lane & 15, lq = lane >> 4;

    f32x4 acc[4][4];
    #pragma unroll
    for (int mt = 0; mt < 4; ++mt)
        #pragma unroll
        for (int nt = 0; nt < 4; ++nt)
            acc[mt][nt] = {0.f, 0.f, 0.f, 0.f};

    for (int kt = 0; kt < 4; ++kt){
        #pragma unroll
        for (int it = 0; it < 8; ++it){
            int v = it * 256 + tid;
            int r = v >> 4, c = v & 15;
            int soff = r * 128 + ((c ^ (r & 15)) << 3);
            int4 av = {0, 0, 0, 0};
            if (row0 + r < M)
                av = *(const int4*)(A + (size_t)(row0 + r) * 512 + kt * 128 + (c << 3));
            *(int4*)(&As[soff]) = av;
            int4 bv = *(const int4*)(BT + (size_t)r * 512 + kt * 128 + (c << 3));
            *(int4*)(&Bs[soff]) = bv;
        }
        __syncthreads();

        #pragma unroll
        for (int kk = 0; kk < 4; ++kk){
            int kc = kk * 4 + lq;
            bf16x8 a[4], b2[4];
            #pragma unroll
            for (int mt = 0; mt < 4; ++mt){
                int r = wm + mt * 16 + lm;
                a[mt] = *(const bf16x8*)(&As[r * 128 + ((kc ^ (r & 15)) << 3)]);
            }
            #pragma unroll
            for (int nt = 0; nt < 4; ++nt){
                int r = wn + nt * 16 + lm;
                b2[nt] = *(const bf16x8*)(&Bs[r * 128 + ((kc ^ (r & 15)) << 3)]);
            }
            #pragma unroll
            for (int mt = 0; mt < 4; ++mt)
                #pragma unroll
                for (int nt = 0; nt < 4; ++nt)
                    acc[mt][nt] = __builtin_amdgcn_mfma_f32_16x16x32_bf16(
                        a[mt], b2[nt], acc[mt][nt], 0, 0, 0);
        }
        __syncthreads();
    }

    if (!doLN){
        #pragma unroll
        for (int mt = 0; mt < 4; ++mt){
            #pragma unroll
            for (int nt = 0; nt < 4; ++nt){
                int col = wn + nt * 16 + lm;
                #pragma unroll
                for (int r = 0; r < 4; ++r){
                    int row = row0 + wm + mt * 16 + lq * 4 + r;
                    if (row < M)
                        outbuf[(size_t)row * 128 + col] = acc[mt][nt][r] + bias[col];
                }
            }
        }
    } else {
        // fused LN+ReLU epilogue. Reuse As for partial sums, Bs for mu/scale.
        float* S1 = (float*)As;          // [128][32] sum partials
        float* S2 = S1 + 4096;           // [128][32] sumsq partials
        float* MS = (float*)Bs;          // mu[128], sc[128]
        const int half = wn >> 6;        // 0 or 1
        const int slot = half * 16 + lm;
        float bv[4];
        #pragma unroll
        for (int nt = 0; nt < 4; ++nt) bv[nt] = bias[wn + nt * 16 + lm];
        #pragma unroll
        for (int mt = 0; mt < 4; ++mt){
            #pragma unroll
            for (int r = 0; r < 4; ++r){
                int rl = wm + mt * 16 + lq * 4 + r;
                float ps = 0.f, pq = 0.f;
                #pragma unroll
                for (int nt = 0; nt < 4; ++nt){
                    float v = acc[mt][nt][r] + bv[nt];
                    ps += v; pq += v * v;
                }
                S1[rl * 32 + slot] = ps;
                S2[rl * 32 + slot] = pq;
            }
        }
        __syncthreads();
        if (tid < 128){
            float s = 0.f, sq = 0.f;
            #pragma unroll
            for (int j = 0; j < 32; ++j){
                s  += S1[tid * 32 + j];
                sq += S2[tid * 32 + j];
            }
            float mu = s * (1.0f / 128.0f);
            float var = sq * (1.0f / 128.0f) - mu * mu;
            MS[tid] = mu;
            MS[128 + tid] = rsqrtf(var + 1e-5f);
        }
        __syncthreads();
        float gv[4], bbv[4];
        #pragma unroll
        for (int nt = 0; nt < 4; ++nt){
            int col = wn + nt * 16 + lm;
            gv[nt] = g[col]; bbv[nt] = b[col];
        }
        #pragma unroll
        for (int mt = 0; mt < 4; ++mt){
            #pragma unroll
            for (int r = 0; r < 4; ++r){
                int rl = wm + mt * 16 + lq * 4 + r;
                int row = row0 + rl;
                if (row < M){
                    float mu = MS[rl], sc = MS[128 + rl];
                    #pragma unroll
                    for (int nt = 0; nt < 4; ++nt){
                        int col = wn + nt * 16 + lm;
                        float v = acc[mt][nt][r] + bv[nt];
                        float y = fmaxf((v - mu) * sc * gv[nt] + bbv[nt], 0.0f);
                        Ap[(size_t)row * 512 + col] = __float2bfloat16(y);
                    }
                }
            }
        }
    }
}

extern "C" void kernel_launch(void* const* d_in, const int* in_sizes, int n_in,
                              void* d_out, int out_size, void* d_ws, size_t ws_size,
                              hipStream_t stream) {
    const float* x     = (const float*)d_in[0];
    const int*   ei    = (const int*)d_in[1];
    const float* asp   = (const float*)d_in[2];
    const float* actx  = (const float*)d_in[3];
    const float* alat  = (const float*)d_in[4];
    const float* wsp   = (const float*)d_in[5];
    const float* wctx  = (const float*)d_in[6];
    const float* wlat  = (const float*)d_in[7];
    const float* W3    = (const float*)d_in[8];
    const float* Wself = (const float*)d_in[9];
    const float* bias  = (const float*)d_in[10];
    const float* dpow  = (const float*)d_in[11];
    const float* lng   = (const float*)d_in[12];
    const float* lnb   = (const float*)d_in[13];

    const int N = in_sizes[0] / 128;
    const int E = in_sizes[1] / 2;
    const int L = in_sizes[8] / (3 * 128 * 128);
    const int NB = cdiv(N, BK);
    const int* src = ei;
    const int* tgt = ei + E;

    // workspace carve (256B-aligned) — identical layout to rounds 2/3 (passed)
    char* p = (char*)d_ws;
    auto alloc = [&](size_t bytes) -> void* {
        void* r = (void*)p;
        p += (bytes + 255) & ~(size_t)255;
        return r;
    };
    int*   rs       = (int*)  alloc((size_t)(N + 1) * 4);
    int*   gcnt     = (int*)  alloc(1024 * 4);
    int*   bbase    = (int*)  alloc(1025 * 4);
    int*   gcur     = (int*)  alloc(1024 * 4);
    uint2* effo     = (uint2*)alloc((size_t)E * 8);
    float* dinv_all = (float*)alloc((size_t)L * N * 4 * 4);   // [L][N][4] padded
    __hip_bfloat16* Ap = (__hip_bfloat16*)alloc((size_t)N * 512 * 2);  // [x|Y0|Y1|Y2]
    __hip_bfloat16* BT = (__hip_bfloat16*)alloc((size_t)L * 128 * 512 * 2);
    // binned (E*16B) aliased onto Ap: dead before k_prep writes Ap (stream-ordered).
    uint4* binned = (uint4*)Ap;

    // ---- prep: bucketed counting-sort CSR build (deg/dinv fused into k_bucket) ----
    hipMemsetAsync(gcnt, 0, 1024 * 4, stream);
    k_bcnt0 <<<cdiv(E, 4096), 256, 0, stream>>>(tgt, gcnt, E, NB);
    k_bscan <<<1, 256, 0, stream>>>(gcnt, bbase, gcur, rs, N, E);
    k_bin   <<<cdiv(E, 4096), 256, 0, stream>>>(src, tgt, asp, actx, alat, wsp, wctx, wlat,
                                                gcur, binned, E, NB);
    k_bucket<<<NB, 256, 0, stream>>>(binned, bbase, dpow, effo, rs, dinv_all, N, L);
    {
        int nx = N * 128, nw = L * 65536;
        k_prep<<<cdiv(nx + nw, 256), 256, 0, stream>>>(x, Ap, Wself, W3, BT, nx, nw);
    }

    // ---- layers ----
    for (int l = 0; l < L; ++l){
        int doLN = (l < L - 1) ? 1 : 0;
        const float4* dinv_l = (const float4*)dinv_all + (size_t)l * N;
        k_msg <<<cdiv(N, 4), 256, 0, stream>>>(Ap, effo, rs, dinv_l, N);
        k_gemm<<<cdiv(N, 128), 256, 0, stream>>>(Ap, BT + (size_t)l * 65536,
                                                 bias + l * 128, (float*)d_out, N,
                                                 doLN, lng, lnb, Ap);
    }
}

// Round 6
// 351.699 us; speedup vs baseline: 1.0841x; 1.0841x over previous
//
#include <hip/hip_runtime.h>
#include <hip/hip_bf16.h>

typedef short bf16x8 __attribute__((ext_vector_type(8)));
typedef float f32x4 __attribute__((ext_vector_type(4)));

#define BSH 7            // 128 targets per bucket
#define BK  (1 << BSH)

static inline int cdiv(int a, int b){ return (a + b - 1) / b; }

__device__ __forceinline__ unsigned pack_bf16_hi(float v){
    return ((unsigned)__bfloat16_as_ushort(__float2bfloat16(v))) << 16;
}
__device__ __forceinline__ float bf16hi_to_f32(unsigned bits_hi16){
    return __uint_as_float(bits_hi16);  // bf16 bits already in [31:16]
}

// ---------- pass 0: global bucket histogram (LDS-privatized) ----------
__global__ __launch_bounds__(256) void k_bcnt0(const int* __restrict__ tgt,
                                               int* __restrict__ gcnt, int E, int NB){
    __shared__ int lh[1024];
    int tid = threadIdx.x;
    for (int b = tid; b < 1024; b += 256) lh[b] = 0;
    __syncthreads();
    int c0 = blockIdx.x * 4096;
    #pragma unroll
    for (int u = 0; u < 16; ++u){
        int e = c0 + u * 256 + tid;
        if (e < E) atomicAdd(&lh[tgt[e] >> BSH], 1);
    }
    __syncthreads();
    for (int b = tid; b < NB; b += 256){
        int c = lh[b];
        if (c) atomicAdd(&gcnt[b], c);
    }
}

// ---------- pass 0.5: scan bucket counts -> bases (= CSR bucket bases) ----------
__global__ __launch_bounds__(256) void k_bscan(const int* __restrict__ gcnt,
                                               int* __restrict__ bbase,
                                               int* __restrict__ gcur,
                                               int* __restrict__ rs,
                                               int N, int E){
    __shared__ int sc[256];
    int tid = threadIdx.x;
    int b0 = tid * 4;
    int v0 = gcnt[b0], v1 = gcnt[b0 + 1], v2 = gcnt[b0 + 2], v3 = gcnt[b0 + 3];
    int t3 = v0 + v1 + v2 + v3;
    sc[tid] = t3;
    __syncthreads();
    for (int off = 1; off < 256; off <<= 1){
        int x = (tid >= off) ? sc[tid - off] : 0;
        __syncthreads();
        sc[tid] += x;
        __syncthreads();
    }
    int ex = sc[tid] - t3;
    bbase[b0]     = ex;
    bbase[b0 + 1] = ex + v0;
    bbase[b0 + 2] = ex + v0 + v1;
    bbase[b0 + 3] = ex + v0 + v1 + v2;
    gcur[b0] = bbase[b0]; gcur[b0 + 1] = bbase[b0 + 1];
    gcur[b0 + 2] = bbase[b0 + 2]; gcur[b0 + 3] = bbase[b0 + 3];
    if (tid == 255) bbase[1024] = sc[255];   // == E
    if (tid == 0)   rs[N] = E;
}

// ---------- pass 1: bin edges into bucket-contiguous regions (direct write) ----------
__global__ __launch_bounds__(256) void k_bin(
        const int* __restrict__ src, const int* __restrict__ tgt,
        const float* __restrict__ asp, const float* __restrict__ actx,
        const float* __restrict__ alat, const float* __restrict__ wsp,
        const float* __restrict__ wctx, const float* __restrict__ wlat,
        int* __restrict__ gcur, uint4* __restrict__ binned, int E, int NB){
    __shared__ int lh[1024], lc[1024], gb[1024];
    int tid = threadIdx.x;
    int c0 = blockIdx.x * 4096;
    for (int b = tid; b < 1024; b += 256){ lh[b] = 0; lc[b] = 0; }
    __syncthreads();
    #pragma unroll
    for (int u = 0; u < 16; ++u){
        int e = c0 + u * 256 + tid;
        if (e < E) atomicAdd(&lh[tgt[e] >> BSH], 1);
    }
    __syncthreads();
    for (int b = tid; b < NB; b += 256){
        int c = lh[b];
        gb[b] = c ? atomicAdd(&gcur[b], c) : 0;
    }
    __syncthreads();
    #pragma unroll
    for (int u = 0; u < 16; ++u){
        int e = c0 + u * 256 + tid;
        if (e < E){
            int t = tgt[e];
            int b = t >> BSH;
            int p = gb[b] + atomicAdd(&lc[b], 1);
            uint4 o;
            o.x = (unsigned)src[e] | pack_bf16_hi(asp[e] * wsp[e]);
            o.y = (pack_bf16_hi(actx[e] * wctx[e]) >> 16) | pack_bf16_hi(alat[e] * wlat[e]);
            o.z = (unsigned)t;
            o.w = 0u;
            binned[p] = o;
        }
    }
}

// ---------- pass 2: per-bucket CSR finalize (writes rs + final effo)
//            + fused per-target deg sums -> dinv_all for ALL layers ----------
__global__ __launch_bounds__(256) void k_bucket(
        const uint4* __restrict__ binned, const int* __restrict__ bbase,
        const float* __restrict__ dp,        // [L*3]
        uint2* __restrict__ effo, int* __restrict__ rs,
        float* __restrict__ dinv_all,        // [L][N][3]
        int N, int L){
    __shared__ int th[128], sc2[128], cur[128];
    __shared__ float sm[384];
    int tid = threadIdx.x;
    int b = blockIdx.x;
    int t0 = b << BSH;
    int ebeg = bbase[b], eend = bbase[b + 1];
    if (tid < 128) th[tid] = 0;
    for (int j = tid; j < 384; j += 256) sm[j] = 0.f;
    __syncthreads();
    for (int i = ebeg + tid; i < eend; i += 256)
        atomicAdd(&th[(int)binned[i].z - t0], 1);
    __syncthreads();
    int v = (tid < 128) ? th[tid] : 0;
    if (tid < 128) sc2[tid] = v;
    __syncthreads();
    for (int off = 1; off < 128; off <<= 1){
        int x = (tid >= off && tid < 128) ? sc2[tid - off] : 0;
        __syncthreads();
        if (tid < 128) sc2[tid] += x;
        __syncthreads();
    }
    if (tid < 128){
        int exv = sc2[tid] - v;
        cur[tid] = exv;
        int t = t0 + tid;
        if (t < N) rs[t] = ebeg + exv;
    }
    __syncthreads();
    for (int i = ebeg + tid; i < eend; i += 256){
        uint4 r = binned[i];
        int loc = (int)r.z - t0;
        int p = atomicAdd(&cur[loc], 1);
        uint2 o = {r.x, r.y};
        effo[ebeg + p] = o;
        atomicAdd(&sm[loc * 3 + 0], bf16hi_to_f32(r.x & 0xFFFF0000u));
        atomicAdd(&sm[loc * 3 + 1], bf16hi_to_f32(r.y << 16));
        atomicAdd(&sm[loc * 3 + 2], bf16hi_to_f32(r.y & 0xFFFF0000u));
    }
    __syncthreads();
    if (tid < 128){
        int t = t0 + tid;
        if (t < N){
            float d0 = fmaxf(1.f + sm[tid * 3 + 0], 1e-6f);
            float d1 = fmaxf(1.f + sm[tid * 3 + 1], 1e-6f);
            float d2 = fmaxf(1.f + sm[tid * 3 + 2], 1e-6f);
            for (int l = 0; l < L; ++l){
                size_t base = ((size_t)l * N + t) * 3;
                dinv_all[base + 0] = powf(d0, dp[l * 3 + 0]);
                dinv_all[base + 1] = powf(d1, dp[l * 3 + 1]);
                dinv_all[base + 2] = powf(d2, dp[l * 3 + 2]);
            }
        }
    }
}

// ---------------- nv for ALL layers: nv[l*E+e] = {src, eff_c * dinv_c[l][src]} ----
// (round-0 proven: keeps k_msg's inner loop free of dependent dinv loads)
__global__ void k_normv(const uint2* __restrict__ effo,
                        const float* __restrict__ dinv_all,  // [L][N][3]
                        uint2* __restrict__ nv, int E, int N, int L){
    int i = blockIdx.x * 256 + threadIdx.x;
    if (i >= L * E) return;
    int l = i / E;
    int e = i - l * E;
    const float* dinv = dinv_all + (size_t)l * N * 3;
    uint2 v = effo[e];
    unsigned s = v.x & 0xFFFFu;
    float e0 = bf16hi_to_f32(v.x & 0xFFFF0000u);
    float e1 = bf16hi_to_f32(v.y << 16);
    float e2 = bf16hi_to_f32(v.y & 0xFFFF0000u);
    float n0 = e0 * dinv[3 * s + 0];
    float n1 = e1 * dinv[3 * s + 1];
    float n2 = e2 * dinv[3 * s + 2];
    uint2 o;
    o.x = s | pack_bf16_hi(n0);
    o.y = (pack_bf16_hi(n1) >> 16) | pack_bf16_hi(n2);
    nv[i] = o;
}

// -------- merged prep: x (fp32) -> xg (bf16 compact [N][128])  AND  BT concat ----
__global__ void k_prep(const float* __restrict__ x, __hip_bfloat16* __restrict__ xg,
                       const float* __restrict__ Wself, const float* __restrict__ W3,
                       __hip_bfloat16* __restrict__ BT, int nx, int nw){
    int i = blockIdx.x * 256 + threadIdx.x;
    if (i < nx){
        xg[i] = __float2bfloat16(x[i]);
    } else {
        int q = i - nx;
        if (q < nw){
            int l = q >> 16, r = q & 65535;
            int j = r >> 9, k = r & 511;
            float v;
            if (k < 128) v = Wself[l * 16384 + k * 128 + j];
            else {
                int c = (k >> 7) - 1, kk = k & 127;
                v = W3[l * 49152 + (c * 128 + kk) * 128 + j];
            }
            BT[q] = __float2bfloat16(v);
        }
    }
}

// ---------------- aggregate: Y_c[t] = dt_c * sum_e nv_c[e] * x[src[e]] ----------
// round-0 proven structure (wave/target, 2 cols/lane, unroll-8, 28 VGPR, 62% occ).
// Gather source is COMPACT xg (256B row stride -> full L2 set utilization; the old
// 1KB-stride Ap left addr bits [8:9]=0 on every x row = 1/4 of L2 sets).
__global__ __launch_bounds__(256) void k_msg(
        const __hip_bfloat16* __restrict__ xg,  // [N][128] bf16 compact
        __hip_bfloat16* __restrict__ Yg,        // [N][384] bf16 compact (out)
        const uint2* __restrict__ nv,           // [E] packed, CSR order (this layer)
        const int* __restrict__ rs,             // [N+1]
        const float* __restrict__ dinv,         // [N][3] (this layer)
        int N){
    int w = threadIdx.x >> 6, lane = threadIdx.x & 63;
    int t = blockIdx.x * 4 + w;
    if (t >= N) return;
    float ax0 = 0.f, ay0 = 0.f, ax1 = 0.f, ay1 = 0.f, ax2 = 0.f, ay2 = 0.f;
    int beg = rs[t], end = rs[t + 1];
    int i = beg;
    for (; i + 8 <= end; i += 8){
        uint2 m[8];
        #pragma unroll
        for (int u = 0; u < 8; ++u) m[u] = nv[i + u];
        float2 f[8];
        #pragma unroll
        for (int u = 0; u < 8; ++u){
            const __hip_bfloat162* p =
                (const __hip_bfloat162*)(xg + (size_t)(m[u].x & 0xFFFFu) * 128);
            f[u] = __bfloat1622float2(p[lane]);
        }
        #pragma unroll
        for (int u = 0; u < 8; ++u){
            float n0 = bf16hi_to_f32(m[u].x & 0xFFFF0000u);
            float n1 = bf16hi_to_f32(m[u].y << 16);
            float n2 = bf16hi_to_f32(m[u].y & 0xFFFF0000u);
            ax0 += n0 * f[u].x; ay0 += n0 * f[u].y;
            ax1 += n1 * f[u].x; ay1 += n1 * f[u].y;
            ax2 += n2 * f[u].x; ay2 += n2 * f[u].y;
        }
    }
    for (; i < end; ++i){
        uint2 m = nv[i];
        const __hip_bfloat162* p =
            (const __hip_bfloat162*)(xg + (size_t)(m.x & 0xFFFFu) * 128);
        float2 fv = __bfloat1622float2(p[lane]);
        float n0 = bf16hi_to_f32(m.x & 0xFFFF0000u);
        float n1 = bf16hi_to_f32(m.y << 16);
        float n2 = bf16hi_to_f32(m.y & 0xFFFF0000u);
        ax0 += n0 * fv.x; ay0 += n0 * fv.y;
        ax1 += n1 * fv.x; ay1 += n1 * fv.y;
        ax2 += n2 * fv.x; ay2 += n2 * fv.y;
    }
    float dt0 = dinv[3 * t], dt1 = dinv[3 * t + 1], dt2 = dinv[3 * t + 2];
    __hip_bfloat162* yo = (__hip_bfloat162*)(Yg + (size_t)t * 384) + lane;
    float2 r0 = {dt0 * ax0, dt0 * ay0};
    float2 r1 = {dt1 * ax1, dt1 * ay1};
    float2 r2 = {dt2 * ax2, dt2 * ay2};
    yo[0]   = __float22bfloat162_rn(r0);
    yo[64]  = __float22bfloat162_rn(r1);
    yo[128] = __float22bfloat162_rn(r2);
}

// ---------------- GEMM: out = [xg|Yg][M,512] @ B[512,128] + bias; opt fused LN+ReLU
// (round-2 int4-vector staging; A split across compact xg (kt=0) / Yg (kt=1..3))
__global__ __launch_bounds__(256) void k_gemm(
        const __hip_bfloat16* __restrict__ Yg,  // [M,384] bf16
        const __hip_bfloat16* __restrict__ BT,  // [128,512] bf16 ([j][k])
        const float* __restrict__ bias,         // [128] fp32
        float* __restrict__ outbuf,             // [M,128] (doLN==0)
        int M, int doLN,
        const float* __restrict__ g, const float* __restrict__ b,
        __hip_bfloat16* __restrict__ xg){       // [M,128]: A kt=0 source; LN target
    __shared__ __hip_bfloat16 As[128 * 128];
    __shared__ __hip_bfloat16 Bs[128 * 128];
    const int tid = threadIdx.x;
    const int row0 = blockIdx.x * 128;
    const int w = tid >> 6, lane = tid & 63;
    const int wm = (w & 1) * 64, wn = (w >> 1) * 64;
    const int lm = lane & 15, lq = lane >> 4;

    f32x4 acc[4][4];
    #pragma unroll
    for (int mt = 0; mt < 4; ++mt)
        #pragma unroll
        for (int nt = 0; nt < 4; ++nt)
            acc[mt][nt] = {0.f, 0.f, 0.f, 0.f};

    for (int kt = 0; kt < 4; ++kt){
        #pragma unroll
        for (int it = 0; it < 8; ++it){
            int v = it * 256 + tid;
            int r = v >> 4, c = v & 15;
            int soff = r * 128 + ((c ^ (r & 15)) << 3);
            int4 av = {0, 0, 0, 0};
            if (row0 + r < M){
                if (kt == 0)
                    av = *(const int4*)(xg + (size_t)(row0 + r) * 128 + (c << 3));
                else
                    av = *(const int4*)(Yg + (size_t)(row0 + r) * 384
                                        + (kt - 1) * 128 + (c << 3));
            }
            *(int4*)(&As[soff]) = av;
            int4 bv = *(const int4*)(BT + (size_t)r * 512 + kt * 128 + (c << 3));
            *(int4*)(&Bs[soff]) = bv;
        }
        __syncthreads();

        #pragma unroll
        for (int kk = 0; kk < 4; ++kk){
            int kc = kk * 4 + lq;
            bf16x8 a[4], b2[4];
            #pragma unroll
            for (int mt = 0; mt < 4; ++mt){
                int r = wm + mt * 16 + lm;
                a[mt] = *(const bf16x8*)(&As[r * 128 + ((kc ^ (r & 15)) << 3)]);
            }
            #pragma unroll
            for (int nt = 0; nt < 4; ++nt){
                int r = wn + nt * 16 + lm;
                b2[nt] = *(const bf16x8*)(&Bs[r * 128 + ((kc ^ (r & 15)) << 3)]);
            }
            #pragma unroll
            for (int mt = 0; mt < 4; ++mt)
                #pragma unroll
                for (int nt = 0; nt < 4; ++nt)
                    acc[mt][nt] = __builtin_amdgcn_mfma_f32_16x16x32_bf16(
                        a[mt], b2[nt], acc[mt][nt], 0, 0, 0);
        }
        __syncthreads();
    }

    if (!doLN){
        #pragma unroll
        for (int mt = 0; mt < 4; ++mt){
            #pragma unroll
            for (int nt = 0; nt < 4; ++nt){
                int col = wn + nt * 16 + lm;
                #pragma unroll
                for (int r = 0; r < 4; ++r){
                    int row = row0 + wm + mt * 16 + lq * 4 + r;
                    if (row < M)
                        outbuf[(size_t)row * 128 + col] = acc[mt][nt][r] + bias[col];
                }
            }
        }
    } else {
        // fused LN+ReLU epilogue. Reuse As for partial sums, Bs for mu/scale.
        float* S1 = (float*)As;          // [128][32] sum partials
        float* S2 = S1 + 4096;           // [128][32] sumsq partials
        float* MS = (float*)Bs;          // mu[128], sc[128]
        const int half = wn >> 6;        // 0 or 1
        const int slot = half * 16 + lm;
        float bv[4];
        #pragma unroll
        for (int nt = 0; nt < 4; ++nt) bv[nt] = bias[wn + nt * 16 + lm];
        #pragma unroll
        for (int mt = 0; mt < 4; ++mt){
            #pragma unroll
            for (int r = 0; r < 4; ++r){
                int rl = wm + mt * 16 + lq * 4 + r;
                float ps = 0.f, pq = 0.f;
                #pragma unroll
                for (int nt = 0; nt < 4; ++nt){
                    float v = acc[mt][nt][r] + bv[nt];
                    ps += v; pq += v * v;
                }
                S1[rl * 32 + slot] = ps;
                S2[rl * 32 + slot] = pq;
            }
        }
        __syncthreads();
        if (tid < 128){
            float s = 0.f, sq = 0.f;
            #pragma unroll
            for (int j = 0; j < 32; ++j){
                s  += S1[tid * 32 + j];
                sq += S2[tid * 32 + j];
            }
            float mu = s * (1.0f / 128.0f);
            float var = sq * (1.0f / 128.0f) - mu * mu;
            MS[tid] = mu;
            MS[128 + tid] = rsqrtf(var + 1e-5f);
        }
        __syncthreads();
        float gv[4], bbv[4];
        #pragma unroll
        for (int nt = 0; nt < 4; ++nt){
            int col = wn + nt * 16 + lm;
            gv[nt] = g[col]; bbv[nt] = b[col];
        }
        #pragma unroll
        for (int mt = 0; mt < 4; ++mt){
            #pragma unroll
            for (int r = 0; r < 4; ++r){
                int rl = wm + mt * 16 + lq * 4 + r;
                int row = row0 + rl;
                if (row < M){
                    float mu = MS[rl], sc = MS[128 + rl];
                    #pragma unroll
                    for (int nt = 0; nt < 4; ++nt){
                        int col = wn + nt * 16 + lm;
                        float v = acc[mt][nt][r] + bv[nt];
                        float y = fmaxf((v - mu) * sc * gv[nt] + bbv[nt], 0.0f);
                        xg[(size_t)row * 128 + col] = __float2bfloat16(y);
                    }
                }
            }
        }
    }
}

extern "C" void kernel_launch(void* const* d_in, const int* in_sizes, int n_in,
                              void* d_out, int out_size, void* d_ws, size_t ws_size,
                              hipStream_t stream) {
    const float* x     = (const float*)d_in[0];
    const int*   ei    = (const int*)d_in[1];
    const float* asp   = (const float*)d_in[2];
    const float* actx  = (const float*)d_in[3];
    const float* alat  = (const float*)d_in[4];
    const float* wsp   = (const float*)d_in[5];
    const float* wctx  = (const float*)d_in[6];
    const float* wlat  = (const float*)d_in[7];
    const float* W3    = (const float*)d_in[8];
    const float* Wself = (const float*)d_in[9];
    const float* bias  = (const float*)d_in[10];
    const float* dpow  = (const float*)d_in[11];
    const float* lng   = (const float*)d_in[12];
    const float* lnb   = (const float*)d_in[13];

    const int N = in_sizes[0] / 128;
    const int E = in_sizes[1] / 2;
    const int L = in_sizes[8] / (3 * 128 * 128);
    const int NB = cdiv(N, BK);
    const int* src = ei;
    const int* tgt = ei + E;

    // workspace carve (256B-aligned) — footprint == round-0 proven (~77 MB)
    char* p = (char*)d_ws;
    auto alloc = [&](size_t bytes) -> void* {
        void* r = (void*)p;
        p += (bytes + 255) & ~(size_t)255;
        return r;
    };
    int*   rs       = (int*)  alloc((size_t)(N + 1) * 4);
    int*   gcnt     = (int*)  alloc(1024 * 4);
    int*   bbase    = (int*)  alloc(1025 * 4);
    int*   gcur     = (int*)  alloc(1024 * 4);
    uint2* effo     = (uint2*)alloc((size_t)E * 8);
    size_t nv_bytes = (size_t)L * E * 8, bn_bytes = (size_t)E * 16;
    uint2* nv       = (uint2*)alloc(nv_bytes > bn_bytes ? nv_bytes : bn_bytes);
    float* dinv_all = (float*)alloc((size_t)L * N * 3 * 4);   // [L][N][3]
    __hip_bfloat16* xg = (__hip_bfloat16*)alloc((size_t)N * 128 * 2);  // [N][128]
    __hip_bfloat16* Yg = (__hip_bfloat16*)alloc((size_t)N * 384 * 2);  // [N][384]
    __hip_bfloat16* BT = (__hip_bfloat16*)alloc((size_t)L * 128 * 512 * 2);
    // binned (E*16B) aliased onto nv: dead before k_normv writes nv (round-0 proven)
    uint4* binned = (uint4*)nv;

    // ---- prep: bucketed counting-sort CSR build (deg/dinv fused into k_bucket) ----
    hipMemsetAsync(gcnt, 0, 1024 * 4, stream);
    k_bcnt0 <<<cdiv(E, 4096), 256, 0, stream>>>(tgt, gcnt, E, NB);
    k_bscan <<<1, 256, 0, stream>>>(gcnt, bbase, gcur, rs, N, E);
    k_bin   <<<cdiv(E, 4096), 256, 0, stream>>>(src, tgt, asp, actx, alat, wsp, wctx, wlat,
                                                gcur, binned, E, NB);
    k_bucket<<<NB, 256, 0, stream>>>(binned, bbase, dpow, effo, rs, dinv_all, N, L);
    k_normv <<<cdiv(L * E, 256), 256, 0, stream>>>(effo, dinv_all, nv, E, N, L);
    {
        int nx = N * 128, nw = L * 65536;
        k_prep<<<cdiv(nx + nw, 256), 256, 0, stream>>>(x, xg, Wself, W3, BT, nx, nw);
    }

    // ---- layers ----
    for (int l = 0; l < L; ++l){
        int doLN = (l < L - 1) ? 1 : 0;
        const float* dinv_l = dinv_all + (size_t)l * N * 3;
        k_msg <<<cdiv(N, 4), 256, 0, stream>>>(xg, Yg, nv + (size_t)l * E, rs, dinv_l, N);
        k_gemm<<<cdiv(N, 128), 256, 0, stream>>>(Yg, BT + (size_t)l * 65536,
                                                 bias + l * 128, (float*)d_out, N,
                                                 doLN, lng, lnb, xg);
    }
}